// Round 1
// baseline (1089.051 us; speedup 1.0000x reference)
//
#include <hip/hip_runtime.h>
#include <hip/hip_bf16.h>

typedef unsigned short u16;
typedef unsigned int u32;
typedef __bf16 bf16x8 __attribute__((ext_vector_type(8)));
typedef float f32x4 __attribute__((ext_vector_type(4)));
typedef u16 u16x4 __attribute__((ext_vector_type(4)));

static constexpr int BB = 2, SS = 2048, HIDC = 2048, LATC = 512, NH = 16, HD = 128;
static constexpr int MROWS = BB * SS;  // 4096
static constexpr float NEGV = -1e9f;

__device__ __forceinline__ u16 f2bf(float f) {
  __hip_bfloat16 h = __float2bfloat16(f);
  return __builtin_bit_cast(u16, h);
}
__device__ __forceinline__ float bf2f(u16 u) {
  return __uint_as_float(((u32)u) << 16);
}
__device__ __forceinline__ void load_lds16(const void* g, void* l) {
  __builtin_amdgcn_global_load_lds(
      (const __attribute__((address_space(1))) void*)g,
      (__attribute__((address_space(3))) void*)l, 16, 0, 0);
}

// ---------------- GEMM: C[M][N] (+)= A[M][K] @ Bt[N][K]^T (bf16 MFMA) -------
// MODE 0: C = f32 store; MODE 1: C += f32; MODE 2: Cb = bf16 store
template <int MODE>
__global__ __launch_bounds__(256, 2) void gemm_bt(
    const u16* __restrict__ A, const u16* __restrict__ Bt,
    float* __restrict__ C, u16* __restrict__ Cb, int M, int N, int K) {
  __shared__ u16 As[128 * 64];
  __shared__ u16 Bs[128 * 64];
  const int tid = threadIdx.x;
  const int lane = tid & 63;
  const int wv = tid >> 6;
  const int wr = wv >> 1, wc = wv & 1;
  const int m0 = blockIdx.x * 128, n0 = blockIdx.y * 128;

  f32x4 acc[4][4];
#pragma unroll
  for (int i = 0; i < 4; ++i)
#pragma unroll
    for (int j = 0; j < 4; ++j) acc[i][j] = (f32x4){0.f, 0.f, 0.f, 0.f};

  // Staging map: 4 chunks/thread/matrix. Chunk j lands at LDS elem j*2048+tid*8
  // (row = e>>6, 16B slot = (e>>3)&7). Global source is pre-XOR-swizzled so
  // that LDS slot s of row r holds global k-chunk (s ^ (r&7)).
  int srow[4], sgc[4];
#pragma unroll
  for (int j = 0; j < 4; ++j) {
    int e = j * 2048 + tid * 8;
    int row = e >> 6;
    int slot = (e >> 3) & 7;
    srow[j] = row;
    sgc[j] = (slot ^ (row & 7)) * 8;
  }

  for (int k0 = 0; k0 < K; k0 += 64) {
    __syncthreads();  // previous iteration's reads done before overwrite
#pragma unroll
    for (int j = 0; j < 4; ++j) {
      const u16* ga = A + (size_t)(m0 + srow[j]) * K + k0 + sgc[j];
      const u16* gb = Bt + (size_t)(n0 + srow[j]) * K + k0 + sgc[j];
      load_lds16(ga, &As[j * 2048 + wv * 512]);
      load_lds16(gb, &Bs[j * 2048 + wv * 512]);
    }
    asm volatile("s_waitcnt vmcnt(0)" ::: "memory");
    __syncthreads();

#pragma unroll
    for (int kk = 0; kk < 2; ++kk) {
      bf16x8 afr[4], bfr[4];
      const int kg = kk * 4 + (lane >> 4);
#pragma unroll
      for (int i = 0; i < 4; ++i) {
        int ar = wr * 64 + i * 16 + (lane & 15);
        afr[i] = *(const bf16x8*)&As[ar * 64 + ((kg ^ (ar & 7)) << 3)];
        int br = wc * 64 + i * 16 + (lane & 15);
        bfr[i] = *(const bf16x8*)&Bs[br * 64 + ((kg ^ (br & 7)) << 3)];
      }
#pragma unroll
      for (int mi = 0; mi < 4; ++mi)
#pragma unroll
        for (int ni = 0; ni < 4; ++ni)
          acc[mi][ni] = __builtin_amdgcn_mfma_f32_16x16x32_bf16(
              afr[mi], bfr[ni], acc[mi][ni], 0, 0, 0);
    }
  }

  // Epilogue. C/D frag: col = lane&15, row = (lane>>4)*4 + reg.
#pragma unroll
  for (int mi = 0; mi < 4; ++mi) {
#pragma unroll
    for (int ni = 0; ni < 4; ++ni) {
      const int row = m0 + wr * 64 + mi * 16 + (lane >> 4) * 4;
      const int col = n0 + wc * 64 + ni * 16 + (lane & 15);
#pragma unroll
      for (int r = 0; r < 4; ++r) {
        size_t off = (size_t)(row + r) * N + col;
        if constexpr (MODE == 0) C[off] = acc[mi][ni][r];
        if constexpr (MODE == 1) C[off] += acc[mi][ni][r];
        if constexpr (MODE == 2) Cb[off] = f2bf(acc[mi][ni][r]);
      }
    }
  }
}

// ------------- transpose + convert: W[K][N] f32 -> Wt[N][K] bf16 (hi/lo) ----
__global__ __launch_bounds__(1024) void transpose_split(
    const float* __restrict__ W, u16* __restrict__ Th, u16* __restrict__ Tl,
    int K, int N) {
  __shared__ float t[32][33];
  const int tx = threadIdx.x, ty = threadIdx.y;
  t[ty][tx] = W[(size_t)(blockIdx.y * 32 + ty) * N + blockIdx.x * 32 + tx];
  __syncthreads();
  const float v = t[tx][ty];
  const u16 hi = f2bf(v);
  const u16 lo = f2bf(v - bf2f(hi));
  const size_t o = (size_t)(blockIdx.x * 32 + ty) * K + blockIdx.y * 32 + tx;
  Th[o] = hi;
  Tl[o] = lo;
}

__global__ __launch_bounds__(1024) void transpose_one(
    const float* __restrict__ W, u16* __restrict__ T, int K, int N) {
  __shared__ float t[32][33];
  const int tx = threadIdx.x, ty = threadIdx.y;
  t[ty][tx] = W[(size_t)(blockIdx.y * 32 + ty) * N + blockIdx.x * 32 + tx];
  __syncthreads();
  const size_t o = (size_t)(blockIdx.x * 32 + ty) * K + blockIdx.y * 32 + tx;
  T[o] = f2bf(t[tx][ty]);
}

// ------------- elementwise split: f32 -> bf16 hi + bf16 lo ------------------
__global__ void split_ew(const float* __restrict__ in, u16* __restrict__ hi,
                         u16* __restrict__ lo, int n) {
  const size_t i = ((size_t)blockIdx.x * blockDim.x + threadIdx.x) * 4;
  if (i >= (size_t)n) return;
  f32x4 v = *(const f32x4*)(in + i);
  u16x4 h, l;
#pragma unroll
  for (int e = 0; e < 4; ++e) {
    float f = v[e];
    u16 hh = f2bf(f);
    h[e] = hh;
    l[e] = f2bf(f - bf2f(hh));
  }
  *(u16x4*)(hi + i) = h;
  *(u16x4*)(lo + i) = l;
}

// ------------- banded forgetful top-k attention ------------------------------
// One wave per (b,h,qi) row. Candidates: sink [0,min(16,lo)) ∪ window [lo,qi],
// lo = max(0, qi-127). ncand <= 144. Exact top-k via binary search on the
// monotonic uint image of the f32 scores; keep s >= kth (ties kept, = ref).
__device__ __forceinline__ u32 fmap(float f) {
  u32 b = __float_as_uint(f);
  return (b & 0x80000000u) ? ~b : (b | 0x80000000u);
}

__global__ __launch_bounds__(256) void attn_kernel(
    const float* __restrict__ qf, const float* __restrict__ kf,
    const u16* __restrict__ vb, const int* __restrict__ forget,
    const int* __restrict__ topk, u16* __restrict__ ab) {
  const float scale = 0.08838834764831845f;  // 1/sqrt(128)
  const int tid = threadIdx.x, lane = tid & 63, wv = tid >> 6;
  const int gw = blockIdx.x * 4 + wv;
  const int qi = gw & (SS - 1);
  const int h = (gw >> 11) & (NH - 1);
  const int b = gw >> 15;

  __shared__ float qsh[4][128];
  __shared__ float psh[4][160];

  const size_t qoff = (size_t)(b * SS + qi) * HIDC + h * HD;
  qsh[wv][lane] = qf[qoff + lane];
  qsh[wv][lane + 64] = qf[qoff + lane + 64];
  __syncthreads();

  const int KTOP = topk[0];
  const int lo = qi > 127 ? qi - 127 : 0;
  const int nsink = lo < 16 ? lo : 16;
  const int ncand = nsink + qi - lo + 1;

  float s[3];
  u32 u[3];
#pragma unroll
  for (int j = 0; j < 3; ++j) {
    const int c = lane + 64 * j;
    if (c < ncand) {
      const int key = c < nsink ? c : lo + (c - nsink);
      float sv = NEGV;
      const bool forgot =
          (key >= 16) && (key != qi) && (forget[b * SS + key] != 0);
      if (!forgot) {
        const float* krow = kf + (size_t)(b * SS + key) * HIDC + h * HD;
        float acc = 0.f;
#pragma unroll 8
        for (int d = 0; d < HD; d += 4) {
          f32x4 kv = *(const f32x4*)(krow + d);
          f32x4 qv = *(const f32x4*)(&qsh[wv][d]);
          acc += qv.x * kv.x + qv.y * kv.y + qv.z * kv.z + qv.w * kv.w;
        }
        sv = acc * scale;
      }
      s[j] = sv;
      u[j] = fmap(sv);
    } else {
      s[j] = NEGV;
      u[j] = 0u;  // never counted: search midpoints are >= 1
    }
  }

  // kth = max{t : |{u >= t}| >= KTOP}; if ncand < KTOP falls to 0 => keep all.
  u32 tl = 0u, th = 0xFFFFFFFFu;
  while (tl < th) {
    const u32 mid = tl + ((th - tl) >> 1) + 1u;
    int cnt = __popcll(__ballot(u[0] >= mid)) + __popcll(__ballot(u[1] >= mid)) +
              __popcll(__ballot(u[2] >= mid));
    if (cnt >= KTOP) tl = mid;
    else th = mid - 1u;
  }

  float m = NEGV;
#pragma unroll
  for (int j = 0; j < 3; ++j)
    if (u[j] >= tl) m = fmaxf(m, s[j]);
#pragma unroll
  for (int off = 32; off > 0; off >>= 1) m = fmaxf(m, __shfl_xor(m, off));

  float z = 0.f, pr[3];
#pragma unroll
  for (int j = 0; j < 3; ++j) {
    pr[j] = (u[j] >= tl) ? __expf(s[j] - m) : 0.f;  // exp(-1e9-m) underflows to 0
    z += pr[j];
  }
#pragma unroll
  for (int off = 32; off > 0; off >>= 1) z += __shfl_xor(z, off);
  const float rz = 1.f / z;

#pragma unroll
  for (int j = 0; j < 3; ++j) {
    const int c = lane + 64 * j;
    if (c < ncand) psh[wv][c] = pr[j] * rz;
  }
  asm volatile("s_waitcnt lgkmcnt(0)" ::: "memory");

  float a0 = 0.f, a1 = 0.f;
  const int d0 = 2 * lane;
  for (int c = 0; c < ncand; ++c) {
    const float w = psh[wv][c];  // broadcast read, uniform branch
    if (w != 0.f) {
      const int key = c < nsink ? c : lo + (c - nsink);
      const u32 vv = *(const u32*)(vb + (size_t)(b * SS + key) * HIDC + h * HD + d0);
      a0 = fmaf(w, bf2f((u16)(vv & 0xFFFFu)), a0);
      a1 = fmaf(w, bf2f((u16)(vv >> 16)), a1);
    }
  }
  const u32 packed = ((u32)f2bf(a1) << 16) | (u32)f2bf(a0);
  *(u32*)(ab + qoff + d0) = packed;
}

// ----------------------------------------------------------------------------
extern "C" void kernel_launch(void* const* d_in, const int* in_sizes, int n_in,
                              void* d_out, int out_size, void* d_ws, size_t ws_size,
                              hipStream_t stream) {
  const float* x = (const float*)d_in[0];
  const float* W_q = (const float*)d_in[1];
  const float* W_dkv = (const float*)d_in[2];
  const float* W_uk = (const float*)d_in[3];
  const float* W_uv = (const float*)d_in[4];
  const float* W_o = (const float*)d_in[5];
  const int* forget = (const int*)d_in[6];
  const int* topk = (const int*)d_in[7];
  float* out = (float*)d_out;

  char* p = (char*)d_ws;
  auto take = [&](size_t n) {
    char* r = p;
    p += (n + 255) & ~(size_t)255;
    return r;
  };

  u16* xb_hi = (u16*)take((size_t)MROWS * HIDC * 2);  // 16MB
  u16* xb_lo = (u16*)take((size_t)MROWS * HIDC * 2);  // 16MB
  u16* Wqh = (u16*)take((size_t)HIDC * HIDC * 2);     // 8MB
  u16* Wql = (u16*)take((size_t)HIDC * HIDC * 2);     // 8MB
  u16* Wdh = (u16*)take((size_t)LATC * HIDC * 2);     // 2MB  (W_dkv^T)
  u16* Wdl = (u16*)take((size_t)LATC * HIDC * 2);
  u16* Wukh = (u16*)take((size_t)HIDC * LATC * 2);    // 2MB  (W_uk^T)
  u16* Wukl = (u16*)take((size_t)HIDC * LATC * 2);
  u16* Wuvt = (u16*)take((size_t)HIDC * LATC * 2);    // 2MB
  u16* Wot = (u16*)take((size_t)HIDC * HIDC * 2);     // 8MB
  float* qf = (float*)take((size_t)MROWS * HIDC * 4); // 32MB
  float* cf = (float*)take((size_t)MROWS * LATC * 4); // 8MB
  u16* cbh = (u16*)take((size_t)MROWS * LATC * 2);    // 4MB
  u16* cbl = (u16*)take((size_t)MROWS * LATC * 2);    // 4MB
  u16* vbb = (u16*)take((size_t)MROWS * HIDC * 2);    // 16MB
  // dead-buffer aliases (xb_* dead after c-GEMM; Wq* dead after q-GEMM):
  float* kf = (float*)xb_hi;  // 32MB over xb_hi+xb_lo
  u16* ab = Wqh;              // 16MB over Wqh+Wql

  const dim3 tb(32, 32);
  split_ew<<<dim3((MROWS * HIDC / 4) / 256), dim3(256), 0, stream>>>(
      x, xb_hi, xb_lo, MROWS * HIDC);
  transpose_split<<<dim3(HIDC / 32, HIDC / 32), tb, 0, stream>>>(W_q, Wqh, Wql, HIDC, HIDC);
  transpose_split<<<dim3(LATC / 32, HIDC / 32), tb, 0, stream>>>(W_dkv, Wdh, Wdl, HIDC, LATC);
  transpose_split<<<dim3(HIDC / 32, LATC / 32), tb, 0, stream>>>(W_uk, Wukh, Wukl, LATC, HIDC);
  transpose_one<<<dim3(HIDC / 32, LATC / 32), tb, 0, stream>>>(W_uv, Wuvt, LATC, HIDC);
  transpose_one<<<dim3(HIDC / 32, HIDC / 32), tb, 0, stream>>>(W_o, Wot, HIDC, HIDC);

  const dim3 gq(MROWS / 128, HIDC / 128);  // 32 x 16
  const dim3 gc(MROWS / 128, LATC / 128);  // 32 x 4

  // q = x @ W_q  (split-bf16, 3 passes -> f32-accurate)
  gemm_bt<0><<<gq, 256, 0, stream>>>(xb_hi, Wqh, qf, nullptr, MROWS, HIDC, HIDC);
  gemm_bt<1><<<gq, 256, 0, stream>>>(xb_hi, Wql, qf, nullptr, MROWS, HIDC, HIDC);
  gemm_bt<1><<<gq, 256, 0, stream>>>(xb_lo, Wqh, qf, nullptr, MROWS, HIDC, HIDC);
  // c = x @ W_dkv (split-bf16)
  gemm_bt<0><<<gc, 256, 0, stream>>>(xb_hi, Wdh, cf, nullptr, MROWS, LATC, HIDC);
  gemm_bt<1><<<gc, 256, 0, stream>>>(xb_hi, Wdl, cf, nullptr, MROWS, LATC, HIDC);
  gemm_bt<1><<<gc, 256, 0, stream>>>(xb_lo, Wdh, cf, nullptr, MROWS, LATC, HIDC);
  split_ew<<<dim3((MROWS * LATC / 4) / 256), dim3(256), 0, stream>>>(
      cf, cbh, cbl, MROWS * LATC);
  // k = c @ W_uk (split-bf16)  -- kf aliases xb (dead now)
  gemm_bt<0><<<gq, 256, 0, stream>>>(cbh, Wukh, kf, nullptr, MROWS, HIDC, LATC);
  gemm_bt<1><<<gq, 256, 0, stream>>>(cbh, Wukl, kf, nullptr, MROWS, HIDC, LATC);
  gemm_bt<1><<<gq, 256, 0, stream>>>(cbl, Wukh, kf, nullptr, MROWS, HIDC, LATC);
  // v = c @ W_uv (plain bf16 out)
  gemm_bt<2><<<gq, 256, 0, stream>>>(cbh, Wuvt, nullptr, vbb, MROWS, HIDC, LATC);
  // banded forgetful top-k attention -> ab (bf16), ab aliases Wq (dead now)
  attn_kernel<<<dim3(BB * NH * SS / 4), dim3(256), 0, stream>>>(
      qf, kf, vbb, forget, topk, ab);
  // out = attn_out @ W_o
  gemm_bt<0><<<gq, 256, 0, stream>>>(ab, Wot, out, nullptr, MROWS, HIDC, HIDC);
}

// Round 2
// 644.033 us; speedup vs baseline: 1.6910x; 1.6910x over previous
//
#include <hip/hip_runtime.h>
#include <hip/hip_bf16.h>

typedef unsigned short u16;
typedef unsigned int u32;
typedef unsigned long long u64;
typedef __bf16 bf16x8 __attribute__((ext_vector_type(8)));
typedef float f32x4 __attribute__((ext_vector_type(4)));
typedef u16 u16x4 __attribute__((ext_vector_type(4)));
typedef u16 u16x8 __attribute__((ext_vector_type(8)));

static constexpr int BB = 2, SS = 2048, HIDC = 2048, LATC = 512, NH = 16, HD = 128;
static constexpr int MROWS = BB * SS;  // 4096
static constexpr float NEGV = -1e9f;

__device__ __forceinline__ u16 f2bf(float f) {
  __hip_bfloat16 h = __float2bfloat16(f);
  return __builtin_bit_cast(u16, h);
}
__device__ __forceinline__ float bf2f(u16 u) {
  return __uint_as_float(((u32)u) << 16);
}
__device__ __forceinline__ void load_lds16(const void* g, void* l) {
  __builtin_amdgcn_global_load_lds(
      (const __attribute__((address_space(1))) void*)g,
      (__attribute__((address_space(3))) void*)l, 16, 0, 0);
}

// ---------------- GEMM: C[M][N] (+)= A[M][K] @ Bt[N][K]^T (bf16 MFMA) -------
// MODE 0: C = f32 store; MODE 1: C += f32; MODE 2: Cb = bf16 store
template <int MODE>
__global__ __launch_bounds__(256, 2) void gemm_bt(
    const u16* __restrict__ A, const u16* __restrict__ Bt,
    float* __restrict__ C, u16* __restrict__ Cb, int M, int N, int K) {
  __shared__ u16 As[128 * 64];
  __shared__ u16 Bs[128 * 64];
  const int tid = threadIdx.x;
  const int lane = tid & 63;
  const int wv = tid >> 6;
  const int wr = wv >> 1, wc = wv & 1;
  const int m0 = blockIdx.x * 128, n0 = blockIdx.y * 128;

  f32x4 acc[4][4];
#pragma unroll
  for (int i = 0; i < 4; ++i)
#pragma unroll
    for (int j = 0; j < 4; ++j) acc[i][j] = (f32x4){0.f, 0.f, 0.f, 0.f};

  int srow[4], sgc[4];
#pragma unroll
  for (int j = 0; j < 4; ++j) {
    int e = j * 2048 + tid * 8;
    int row = e >> 6;
    int slot = (e >> 3) & 7;
    srow[j] = row;
    sgc[j] = (slot ^ (row & 7)) * 8;
  }

  for (int k0 = 0; k0 < K; k0 += 64) {
    __syncthreads();
#pragma unroll
    for (int j = 0; j < 4; ++j) {
      const u16* ga = A + (size_t)(m0 + srow[j]) * K + k0 + sgc[j];
      const u16* gb = Bt + (size_t)(n0 + srow[j]) * K + k0 + sgc[j];
      load_lds16(ga, &As[j * 2048 + wv * 512]);
      load_lds16(gb, &Bs[j * 2048 + wv * 512]);
    }
    asm volatile("s_waitcnt vmcnt(0)" ::: "memory");
    __syncthreads();

#pragma unroll
    for (int kk = 0; kk < 2; ++kk) {
      bf16x8 afr[4], bfr[4];
      const int kg = kk * 4 + (lane >> 4);
#pragma unroll
      for (int i = 0; i < 4; ++i) {
        int ar = wr * 64 + i * 16 + (lane & 15);
        afr[i] = *(const bf16x8*)&As[ar * 64 + ((kg ^ (ar & 7)) << 3)];
        int br = wc * 64 + i * 16 + (lane & 15);
        bfr[i] = *(const bf16x8*)&Bs[br * 64 + ((kg ^ (br & 7)) << 3)];
      }
#pragma unroll
      for (int mi = 0; mi < 4; ++mi)
#pragma unroll
        for (int ni = 0; ni < 4; ++ni)
          acc[mi][ni] = __builtin_amdgcn_mfma_f32_16x16x32_bf16(
              afr[mi], bfr[ni], acc[mi][ni], 0, 0, 0);
    }
  }

#pragma unroll
  for (int mi = 0; mi < 4; ++mi) {
#pragma unroll
    for (int ni = 0; ni < 4; ++ni) {
      const int row = m0 + wr * 64 + mi * 16 + (lane >> 4) * 4;
      const int col = n0 + wc * 64 + ni * 16 + (lane & 15);
#pragma unroll
      for (int r = 0; r < 4; ++r) {
        size_t off = (size_t)(row + r) * N + col;
        if constexpr (MODE == 0) C[off] = acc[mi][ni][r];
        if constexpr (MODE == 1) C[off] += acc[mi][ni][r];
        if constexpr (MODE == 2) Cb[off] = f2bf(acc[mi][ni][r]);
      }
    }
  }
}

// ------------- transpose + convert: W[K][N] f32 -> Wt[N][K] bf16 (hi/lo) ----
__global__ __launch_bounds__(1024) void transpose_split(
    const float* __restrict__ W, u16* __restrict__ Th, u16* __restrict__ Tl,
    int K, int N) {
  __shared__ float t[32][33];
  const int tx = threadIdx.x, ty = threadIdx.y;
  t[ty][tx] = W[(size_t)(blockIdx.y * 32 + ty) * N + blockIdx.x * 32 + tx];
  __syncthreads();
  const float v = t[tx][ty];
  const u16 hi = f2bf(v);
  const u16 lo = f2bf(v - bf2f(hi));
  const size_t o = (size_t)(blockIdx.x * 32 + ty) * K + blockIdx.y * 32 + tx;
  Th[o] = hi;
  Tl[o] = lo;
}

__global__ __launch_bounds__(1024) void transpose_one(
    const float* __restrict__ W, u16* __restrict__ T, int K, int N) {
  __shared__ float t[32][33];
  const int tx = threadIdx.x, ty = threadIdx.y;
  t[ty][tx] = W[(size_t)(blockIdx.y * 32 + ty) * N + blockIdx.x * 32 + tx];
  __syncthreads();
  const size_t o = (size_t)(blockIdx.x * 32 + ty) * K + blockIdx.y * 32 + tx;
  T[o] = f2bf(t[tx][ty]);
}

// ------------- elementwise split: f32 -> bf16 hi + bf16 lo ------------------
__global__ void split_ew(const float* __restrict__ in, u16* __restrict__ hi,
                         u16* __restrict__ lo, int n) {
  const size_t i = ((size_t)blockIdx.x * blockDim.x + threadIdx.x) * 4;
  if (i >= (size_t)n) return;
  f32x4 v = *(const f32x4*)(in + i);
  u16x4 h, l;
#pragma unroll
  for (int e = 0; e < 4; ++e) {
    float f = v[e];
    u16 hh = f2bf(f);
    h[e] = hh;
    l[e] = f2bf(f - bf2f(hh));
  }
  *(u16x4*)(hi + i) = h;
  *(u16x4*)(lo + i) = l;
}

// ------------- attention v2: tiled MFMA QK^T + exact top-k + compact PV ------
__device__ __forceinline__ u32 fmap(float f) {
  u32 b = __float_as_uint(f);
  return (b & 0x80000000u) ? ~b : (b | 0x80000000u);
}

// Workgroup: (qblock of 64, h, b). 8 waves. LDS 96KB:
//   Kh/Kl: 64x128 bf16 hi/lo (16KB each, XOR-swizzled 16B chunks)
//   Ssc:   64x256 f32 scores (64KB)
// Aliases on Kh after MFMA: fm[256] ints @0, kcol u16[8][256] @1KB, kw f32[8][256] @5KB
__global__ __launch_bounds__(512, 1) void attn_v2(
    const float* __restrict__ qf, const float* __restrict__ kf,
    const u16* __restrict__ vb, const int* __restrict__ forget,
    const int* __restrict__ topk, u16* __restrict__ ab) {
  __shared__ u16 Kh[64 * 128];
  __shared__ u16 Kl[64 * 128];
  __shared__ float Ssc[64 * 256];
  int* fm = (int*)Kh;
  u16* kcol = Kh + 512;
  float* kw = (float*)(Kh + 2560);

  const float scale = 0.08838834764831845f;  // 1/sqrt(128)
  const int tid = threadIdx.x, lane = tid & 63, wv = tid >> 6;
  const int q0 = blockIdx.x * 64;
  const int h = blockIdx.y, b = blockIdx.z;
  const int mt = wv >> 1, nh = wv & 1;

  // key-tile bases: sink tile + 3 window tiles (contiguous when q0 < 256)
  int kb[4], nt;
  if (q0 >= 256) {
    nt = 4;
    kb[0] = 0; kb[1] = q0 - 128; kb[2] = q0 - 64; kb[3] = q0;
  } else {
    nt = q0 / 64 + 1;
#pragma unroll
    for (int t = 0; t < 4; ++t) kb[t] = t * 64;
  }

  // ---- Q fragments in registers (split hi/lo), rows mt*16+(lane&15) ----
  u16x8 ah[4], al[4];
  {
    const size_t qrow =
        (size_t)(b * SS + q0 + mt * 16 + (lane & 15)) * HIDC + h * HD;
#pragma unroll
    for (int kt = 0; kt < 4; ++kt) {
#pragma unroll
      for (int hf = 0; hf < 2; ++hf) {
        f32x4 v = *(const f32x4*)(qf + qrow + kt * 32 + (lane >> 4) * 8 + hf * 4);
#pragma unroll
        for (int e = 0; e < 4; ++e) {
          u16 hi = f2bf(v[e]);
          ah[kt][hf * 4 + e] = hi;
          al[kt][hf * 4 + e] = f2bf(v[e] - bf2f(hi));
        }
      }
    }
  }

  // ---- key-tile loop: stage K (hi/lo, swizzled) -> MFMA -> Ssc ----
  for (int t = 0; t < nt; ++t) {
    __syncthreads();  // prior tile's Kh/Kl reads done
    for (int idx = tid; idx < 64 * 32; idx += 512) {
      const int row = idx >> 5, c4 = idx & 31;
      f32x4 v = *(const f32x4*)(kf + (size_t)(b * SS + kb[t] + row) * HIDC +
                                h * HD + c4 * 4);
      u16x4 hh, ll;
#pragma unroll
      for (int e = 0; e < 4; ++e) {
        u16 hi = f2bf(v[e]);
        hh[e] = hi;
        ll[e] = f2bf(v[e] - bf2f(hi));
      }
      const int off = row * 128 + (((c4 >> 1) ^ (row & 7)) << 3) + (c4 & 1) * 4;
      *(u16x4*)(Kh + off) = hh;
      *(u16x4*)(Kl + off) = ll;
    }
    __syncthreads();

    f32x4 acc[2];
    acc[0] = (f32x4){0.f, 0.f, 0.f, 0.f};
    acc[1] = (f32x4){0.f, 0.f, 0.f, 0.f};
#pragma unroll
    for (int kt = 0; kt < 4; ++kt) {
      const int kg = kt * 4 + (lane >> 4);
#pragma unroll
      for (int ni = 0; ni < 2; ++ni) {
        const int key = nh * 32 + ni * 16 + (lane & 15);
        const int off = key * 128 + ((kg ^ (key & 7)) << 3);
        bf16x8 bh = *(const bf16x8*)(Kh + off);
        bf16x8 bl = *(const bf16x8*)(Kl + off);
        acc[ni] = __builtin_amdgcn_mfma_f32_16x16x32_bf16(
            __builtin_bit_cast(bf16x8, ah[kt]), bh, acc[ni], 0, 0, 0);
        acc[ni] = __builtin_amdgcn_mfma_f32_16x16x32_bf16(
            __builtin_bit_cast(bf16x8, ah[kt]), bl, acc[ni], 0, 0, 0);
        acc[ni] = __builtin_amdgcn_mfma_f32_16x16x32_bf16(
            __builtin_bit_cast(bf16x8, al[kt]), bh, acc[ni], 0, 0, 0);
      }
    }
#pragma unroll
    for (int ni = 0; ni < 2; ++ni)
#pragma unroll
      for (int r = 0; r < 4; ++r)
        Ssc[(mt * 16 + (lane >> 4) * 4 + r) * 256 + t * 64 + nh * 32 + ni * 16 +
            (lane & 15)] = acc[ni][r] * scale;
  }

  __syncthreads();  // Ssc complete, Kh/Kl dead
  if (tid < 256) {
    const int t = tid >> 6;
    fm[tid] = (t < nt) ? forget[b * SS + kb[t] + (tid & 63)] : 0;
  }
  __syncthreads();

  const int KTOP = topk[0];
  float* kwb = kw + wv * 256;
  u16* kcb = kcol + wv * 256;
  const u64 below = (lane == 63) ? 0x7FFFFFFFFFFFFFFFull
                                 : ((1ull << lane) - 1ull);

  for (int i = 0; i < 8; ++i) {
    const int r = wv * 8 + i, qi = q0 + r;
    float s[4];
    u32 u[4];
    int keyv[4];
#pragma unroll
    for (int j = 0; j < 4; ++j) {
      if (j < nt) {
        const int key = kb[j] + lane;
        keyv[j] = key;
        const bool valid =
            key <= qi && (key >= qi - 127 || key < 16) &&
            !(fm[j * 64 + lane] && key >= 16 && key != qi);
        s[j] = valid ? Ssc[r * 256 + j * 64 + lane] : NEGV;
      } else {
        s[j] = NEGV;
        keyv[j] = 0;
      }
      u[j] = fmap(s[j]);
    }

    u32 tl = 0u, th = 0xFFFFFFFFu;
    while (tl < th) {
      const u32 mid = tl + ((th - tl) >> 1) + 1u;
      const int cnt =
          __popcll(__ballot(u[0] >= mid)) + __popcll(__ballot(u[1] >= mid)) +
          __popcll(__ballot(u[2] >= mid)) + __popcll(__ballot(u[3] >= mid));
      if (cnt >= KTOP) tl = mid;
      else th = mid - 1u;
    }

    float m = NEGV;
#pragma unroll
    for (int j = 0; j < 4; ++j)
      if (u[j] >= tl) m = fmaxf(m, s[j]);
#pragma unroll
    for (int off = 32; off > 0; off >>= 1) m = fmaxf(m, __shfl_xor(m, off));

    float z = 0.f, pr[4];
#pragma unroll
    for (int j = 0; j < 4; ++j) {
      pr[j] = (u[j] >= tl) ? __expf(s[j] - m) : 0.f;
      z += pr[j];
    }
#pragma unroll
    for (int off = 32; off > 0; off >>= 1) z += __shfl_xor(z, off);
    const float rz = 1.f / z;

    // compact kept (weight,key) pairs
    int nk = 0;
#pragma unroll
    for (int j = 0; j < 4; ++j) {
      const float w = pr[j] * rz;
      const u64 mask = __ballot(w > 0.f);
      const int pos = nk + __popcll(mask & below);
      if (w > 0.f) {
        kwb[pos] = w;
        kcb[pos] = (u16)keyv[j];
      }
      nk += __popcll(mask);
    }
    const int pad = (nk + 7) & ~7;
    if (nk + lane < pad) {
      kwb[nk + lane] = 0.f;
      kcb[nk + lane] = 0;
    }

    // PV: batched 8-wide, broadcast weights, coalesced V rows
    float a0 = 0.f, a1 = 0.f;
    const size_t vbase = (size_t)b * SS * HIDC + h * HD + 2 * lane;
    for (int p0 = 0; p0 < pad; p0 += 8) {
      f32x4 w0 = *(const f32x4*)(kwb + p0);
      f32x4 w1 = *(const f32x4*)(kwb + p0 + 4);
      u16x4 c0 = *(const u16x4*)(kcb + p0);
      u16x4 c1 = *(const u16x4*)(kcb + p0 + 4);
#pragma unroll
      for (int e = 0; e < 4; ++e) {
        const u32 vv = *(const u32*)(vb + vbase + (size_t)c0[e] * HIDC);
        a0 = fmaf(w0[e], bf2f((u16)(vv & 0xFFFFu)), a0);
        a1 = fmaf(w0[e], bf2f((u16)(vv >> 16)), a1);
      }
#pragma unroll
      for (int e = 0; e < 4; ++e) {
        const u32 vv = *(const u32*)(vb + vbase + (size_t)c1[e] * HIDC);
        a0 = fmaf(w1[e], bf2f((u16)(vv & 0xFFFFu)), a0);
        a1 = fmaf(w1[e], bf2f((u16)(vv >> 16)), a1);
      }
    }
    const u32 packed = ((u32)f2bf(a1) << 16) | (u32)f2bf(a0);
    *(u32*)(ab + (size_t)(b * SS + qi) * HIDC + h * HD + 2 * lane) = packed;
  }
}

// ----------------------------------------------------------------------------
extern "C" void kernel_launch(void* const* d_in, const int* in_sizes, int n_in,
                              void* d_out, int out_size, void* d_ws, size_t ws_size,
                              hipStream_t stream) {
  const float* x = (const float*)d_in[0];
  const float* W_q = (const float*)d_in[1];
  const float* W_dkv = (const float*)d_in[2];
  const float* W_uk = (const float*)d_in[3];
  const float* W_uv = (const float*)d_in[4];
  const float* W_o = (const float*)d_in[5];
  const int* forget = (const int*)d_in[6];
  const int* topk = (const int*)d_in[7];
  float* out = (float*)d_out;

  char* p = (char*)d_ws;
  auto take = [&](size_t n) {
    char* r = p;
    p += (n + 255) & ~(size_t)255;
    return r;
  };

  u16* xb_hi = (u16*)take((size_t)MROWS * HIDC * 2);  // 16MB
  u16* xb_lo = (u16*)take((size_t)MROWS * HIDC * 2);  // 16MB
  u16* Wqh = (u16*)take((size_t)HIDC * HIDC * 2);     // 8MB
  u16* Wql = (u16*)take((size_t)HIDC * HIDC * 2);     // 8MB
  u16* Wdh = (u16*)take((size_t)LATC * HIDC * 2);     // 2MB  (W_dkv^T)
  u16* Wdl = (u16*)take((size_t)LATC * HIDC * 2);
  u16* Wukh = (u16*)take((size_t)HIDC * LATC * 2);    // 2MB  (W_uk^T)
  u16* Wukl = (u16*)take((size_t)HIDC * LATC * 2);
  u16* Wuvt = (u16*)take((size_t)HIDC * LATC * 2);    // 2MB
  u16* Wot = (u16*)take((size_t)HIDC * HIDC * 2);     // 8MB
  float* qf = (float*)take((size_t)MROWS * HIDC * 4); // 32MB
  float* cf = (float*)take((size_t)MROWS * LATC * 4); // 8MB
  u16* cbh = (u16*)take((size_t)MROWS * LATC * 2);    // 4MB
  u16* cbl = (u16*)take((size_t)MROWS * LATC * 2);    // 4MB
  u16* vbb = (u16*)take((size_t)MROWS * HIDC * 2);    // 16MB
  float* kf = (float*)xb_hi;  // alias: xb dead after c-GEMM
  u16* ab = Wqh;              // alias: Wq dead after q-GEMM

  const dim3 tb(32, 32);
  split_ew<<<dim3((MROWS * HIDC / 4) / 256), dim3(256), 0, stream>>>(
      x, xb_hi, xb_lo, MROWS * HIDC);
  transpose_split<<<dim3(HIDC / 32, HIDC / 32), tb, 0, stream>>>(W_q, Wqh, Wql, HIDC, HIDC);
  transpose_split<<<dim3(LATC / 32, HIDC / 32), tb, 0, stream>>>(W_dkv, Wdh, Wdl, HIDC, LATC);
  transpose_split<<<dim3(HIDC / 32, LATC / 32), tb, 0, stream>>>(W_uk, Wukh, Wukl, LATC, HIDC);
  transpose_one<<<dim3(HIDC / 32, LATC / 32), tb, 0, stream>>>(W_uv, Wuvt, LATC, HIDC);
  transpose_one<<<dim3(HIDC / 32, HIDC / 32), tb, 0, stream>>>(W_o, Wot, HIDC, HIDC);

  const dim3 gq(MROWS / 128, HIDC / 128);  // 32 x 16
  const dim3 gc(MROWS / 128, LATC / 128);  // 32 x 4

  // q = x @ W_q  (split-bf16, 3 passes -> f32-accurate)
  gemm_bt<0><<<gq, 256, 0, stream>>>(xb_hi, Wqh, qf, nullptr, MROWS, HIDC, HIDC);
  gemm_bt<1><<<gq, 256, 0, stream>>>(xb_hi, Wql, qf, nullptr, MROWS, HIDC, HIDC);
  gemm_bt<1><<<gq, 256, 0, stream>>>(xb_lo, Wqh, qf, nullptr, MROWS, HIDC, HIDC);
  // c = x @ W_dkv (split-bf16)
  gemm_bt<0><<<gc, 256, 0, stream>>>(xb_hi, Wdh, cf, nullptr, MROWS, LATC, HIDC);
  gemm_bt<1><<<gc, 256, 0, stream>>>(xb_hi, Wdl, cf, nullptr, MROWS, LATC, HIDC);
  gemm_bt<1><<<gc, 256, 0, stream>>>(xb_lo, Wdh, cf, nullptr, MROWS, LATC, HIDC);
  split_ew<<<dim3((MROWS * LATC / 4) / 256), dim3(256), 0, stream>>>(
      cf, cbh, cbl, MROWS * LATC);
  // k = c @ W_uk (split-bf16)  -- kf aliases xb (dead now)
  gemm_bt<0><<<gq, 256, 0, stream>>>(cbh, Wukh, kf, nullptr, MROWS, HIDC, LATC);
  gemm_bt<1><<<gq, 256, 0, stream>>>(cbh, Wukl, kf, nullptr, MROWS, HIDC, LATC);
  gemm_bt<1><<<gq, 256, 0, stream>>>(cbl, Wukh, kf, nullptr, MROWS, HIDC, LATC);
  // v = c @ W_uv (plain bf16 out)
  gemm_bt<2><<<gq, 256, 0, stream>>>(cbh, Wuvt, nullptr, vbb, MROWS, HIDC, LATC);
  // attention v2 -> ab (bf16), aliases Wq (dead)
  attn_v2<<<dim3(SS / 64, NH, BB), dim3(512), 0, stream>>>(
      qf, kf, vbb, forget, topk, ab);
  // out = attn_out @ W_o
  gemm_bt<0><<<gq, 256, 0, stream>>>(ab, Wot, out, nullptr, MROWS, HIDC, HIDC);
}

// Round 3
// 528.661 us; speedup vs baseline: 2.0600x; 1.2182x over previous
//
#include <hip/hip_runtime.h>
#include <hip/hip_bf16.h>

typedef unsigned short u16;
typedef unsigned int u32;
typedef unsigned long long u64;
typedef __bf16 bf16x8 __attribute__((ext_vector_type(8)));
typedef float f32x4 __attribute__((ext_vector_type(4)));
typedef u16 u16x4 __attribute__((ext_vector_type(4)));
typedef u16 u16x8 __attribute__((ext_vector_type(8)));

static constexpr int BB = 2, SS = 2048, HIDC = 2048, LATC = 512, NH = 16, HD = 128;
static constexpr int MROWS = BB * SS;  // 4096
static constexpr float NEGV = -1e9f;

__device__ __forceinline__ u16 f2bf(float f) {
  __hip_bfloat16 h = __float2bfloat16(f);
  return __builtin_bit_cast(u16, h);
}
__device__ __forceinline__ float bf2f(u16 u) {
  return __uint_as_float(((u32)u) << 16);
}
__device__ __forceinline__ void load_lds16(const void* g, void* l) {
  __builtin_amdgcn_global_load_lds(
      (const __attribute__((address_space(1))) void*)g,
      (__attribute__((address_space(3))) void*)l, 16, 0, 0);
}

// ---------------- GEMM: C[M][N] (+)= A[M][K] @ Bt[N][K]^T (bf16 MFMA) -------
// MODE 0: C = f32 store; MODE 1: C += f32; MODE 2: Cb = bf16 store
template <int MODE>
__global__ __launch_bounds__(256, 2) void gemm_bt(
    const u16* __restrict__ A, const u16* __restrict__ Bt,
    float* __restrict__ C, u16* __restrict__ Cb, int M, int N, int K) {
  __shared__ u16 As[128 * 64];
  __shared__ u16 Bs[128 * 64];
  const int tid = threadIdx.x;
  const int lane = tid & 63;
  const int wv = tid >> 6;
  const int wr = wv >> 1, wc = wv & 1;
  const int m0 = blockIdx.x * 128, n0 = blockIdx.y * 128;

  f32x4 acc[4][4];
#pragma unroll
  for (int i = 0; i < 4; ++i)
#pragma unroll
    for (int j = 0; j < 4; ++j) acc[i][j] = (f32x4){0.f, 0.f, 0.f, 0.f};

  int srow[4], sgc[4];
#pragma unroll
  for (int j = 0; j < 4; ++j) {
    int e = j * 2048 + tid * 8;
    int row = e >> 6;
    int slot = (e >> 3) & 7;
    srow[j] = row;
    sgc[j] = (slot ^ (row & 7)) * 8;
  }

  for (int k0 = 0; k0 < K; k0 += 64) {
    __syncthreads();
#pragma unroll
    for (int j = 0; j < 4; ++j) {
      const u16* ga = A + (size_t)(m0 + srow[j]) * K + k0 + sgc[j];
      const u16* gb = Bt + (size_t)(n0 + srow[j]) * K + k0 + sgc[j];
      load_lds16(ga, &As[j * 2048 + wv * 512]);
      load_lds16(gb, &Bs[j * 2048 + wv * 512]);
    }
    asm volatile("s_waitcnt vmcnt(0)" ::: "memory");
    __syncthreads();

#pragma unroll
    for (int kk = 0; kk < 2; ++kk) {
      bf16x8 afr[4], bfr[4];
      const int kg = kk * 4 + (lane >> 4);
#pragma unroll
      for (int i = 0; i < 4; ++i) {
        int ar = wr * 64 + i * 16 + (lane & 15);
        afr[i] = *(const bf16x8*)&As[ar * 64 + ((kg ^ (ar & 7)) << 3)];
        int br = wc * 64 + i * 16 + (lane & 15);
        bfr[i] = *(const bf16x8*)&Bs[br * 64 + ((kg ^ (br & 7)) << 3)];
      }
#pragma unroll
      for (int mi = 0; mi < 4; ++mi)
#pragma unroll
        for (int ni = 0; ni < 4; ++ni)
          acc[mi][ni] = __builtin_amdgcn_mfma_f32_16x16x32_bf16(
              afr[mi], bfr[ni], acc[mi][ni], 0, 0, 0);
    }
  }

#pragma unroll
  for (int mi = 0; mi < 4; ++mi) {
#pragma unroll
    for (int ni = 0; ni < 4; ++ni) {
      const int row = m0 + wr * 64 + mi * 16 + (lane >> 4) * 4;
      const int col = n0 + wc * 64 + ni * 16 + (lane & 15);
#pragma unroll
      for (int r = 0; r < 4; ++r) {
        size_t off = (size_t)(row + r) * N + col;
        if constexpr (MODE == 0) C[off] = acc[mi][ni][r];
        if constexpr (MODE == 1) C[off] += acc[mi][ni][r];
        if constexpr (MODE == 2) Cb[off] = f2bf(acc[mi][ni][r]);
      }
    }
  }
}

// ------------- transpose + convert: W[K][N] f32 -> Wt[N][K] bf16 (hi/lo) ----
__global__ __launch_bounds__(1024) void transpose_split(
    const float* __restrict__ W, u16* __restrict__ Th, u16* __restrict__ Tl,
    int K, int N) {
  __shared__ float t[32][33];
  const int tx = threadIdx.x, ty = threadIdx.y;
  t[ty][tx] = W[(size_t)(blockIdx.y * 32 + ty) * N + blockIdx.x * 32 + tx];
  __syncthreads();
  const float v = t[tx][ty];
  const u16 hi = f2bf(v);
  const u16 lo = f2bf(v - bf2f(hi));
  const size_t o = (size_t)(blockIdx.x * 32 + ty) * K + blockIdx.y * 32 + tx;
  Th[o] = hi;
  Tl[o] = lo;
}

__global__ __launch_bounds__(1024) void transpose_one(
    const float* __restrict__ W, u16* __restrict__ T, int K, int N) {
  __shared__ float t[32][33];
  const int tx = threadIdx.x, ty = threadIdx.y;
  t[ty][tx] = W[(size_t)(blockIdx.y * 32 + ty) * N + blockIdx.x * 32 + tx];
  __syncthreads();
  const size_t o = (size_t)(blockIdx.x * 32 + ty) * K + blockIdx.y * 32 + tx;
  T[o] = f2bf(t[tx][ty]);
}

// ------------- elementwise split: f32 -> bf16 hi + bf16 lo ------------------
__global__ void split_ew(const float* __restrict__ in, u16* __restrict__ hi,
                         u16* __restrict__ lo, int n) {
  const size_t i = ((size_t)blockIdx.x * blockDim.x + threadIdx.x) * 4;
  if (i >= (size_t)n) return;
  f32x4 v = *(const f32x4*)(in + i);
  u16x4 h, l;
#pragma unroll
  for (int e = 0; e < 4; ++e) {
    float f = v[e];
    u16 hh = f2bf(f);
    h[e] = hh;
    l[e] = f2bf(f - bf2f(hh));
  }
  *(u16x4*)(hi + i) = h;
  *(u16x4*)(lo + i) = l;
}

// ------------- attention v3 --------------------------------------------------
// Per (64q, h, b) block, 8 waves. Tile-at-a-time scores (St 17KB), interleaved
// 8-row exact top-k (binary search on fmap image), P->LDS bf16 (over K area),
// PV via MFMA with V^T tiles staged by global_load_lds (pre-swizzled source).
// LDS 50KB -> 2 blocks/CU.
__device__ __forceinline__ u32 fmap(float f) {
  u32 b = __float_as_uint(f);
  return (b & 0x80000000u) ? ~b : (b | 0x80000000u);
}
__device__ __forceinline__ float unfmap(u32 u) {
  return (u & 0x80000000u) ? __uint_as_float(u ^ 0x80000000u)
                           : __uint_as_float(~u);
}

__global__ __launch_bounds__(512, 4) void attn_v3(
    const float* __restrict__ qf, const float* __restrict__ kf,
    const u16* __restrict__ vt, const int* __restrict__ forget,
    const int* __restrict__ topk, u16* __restrict__ ab) {
  __shared__ u16 KP[2 * 64 * 128];  // 32KB: K hi/lo tiles; later P[64][256]
  __shared__ float St[64 * 68];     // 17KB: per-tile scores; later V^T tile
  __shared__ int fm[256];           // 1KB

  u16* const Kh = KP;
  u16* const Kl = KP + 64 * 128;
  u16* const Pb = KP;          // P bf16 [64][256], slot-XOR swizzled
  u16* const Vts = (u16*)St;   // V^T tile [128 d][64 k], slot-XOR swizzled

  const float scale = 0.08838834764831845f;  // 1/sqrt(128)
  const int tid = threadIdx.x, lane = tid & 63, wv = tid >> 6;
  const int q0 = blockIdx.x * 64;
  const int h = blockIdx.y, b = blockIdx.z;
  const int mt = wv >> 1, nh = wv & 1;  // wave roles (QK and PV)
  const int l15 = lane & 15, lhi = lane >> 4;

  const int nt = (q0 >= 256) ? 4 : (q0 / 64 + 1);
  const int KTOP = topk[0];

  auto kbase = [&](int t) {
    return (q0 >= 256) ? (t == 0 ? 0 : q0 + t * 64 - 192) : t * 64;
  };
  auto stage_vt = [&](int T) {
    const int kbt = kbase(T);
#pragma unroll
    for (int p = 0; p < 2; ++p) {
      const int c = p * 512 + tid;
      const int d = c >> 3, sl = c & 7;
      const u16* src = vt + ((size_t)(b * HIDC + h * HD + d)) * SS + kbt +
                       ((sl ^ (d & 7)) << 3);
      load_lds16(src, Vts + (p * 512 + wv * 64) * 8);
    }
  };

  if (tid < 256) {
    const int t = tid >> 6;
    fm[tid] = (t < nt) ? forget[b * SS + kbase(t) + (tid & 63)] : 0;
  }

  // ---- Q fragments in registers (split hi/lo), rows mt*16+l15 ----
  u16x8 ah[4], al[4];
  {
    const size_t qrow = (size_t)(b * SS + q0 + mt * 16 + l15) * HIDC + h * HD;
#pragma unroll
    for (int kt = 0; kt < 4; ++kt)
#pragma unroll
      for (int hf = 0; hf < 2; ++hf) {
        f32x4 v = *(const f32x4*)(qf + qrow + kt * 32 + lhi * 8 + hf * 4);
#pragma unroll
        for (int e = 0; e < 4; ++e) {
          const u16 hi = f2bf(v[e]);
          ah[kt][hf * 4 + e] = hi;
          al[kt][hf * 4 + e] = f2bf(v[e] - bf2f(hi));
        }
      }
  }

  u32 uu[8][4];
#pragma unroll
  for (int i = 0; i < 8; ++i)
#pragma unroll
    for (int j = 0; j < 4; ++j) uu[i][j] = 0u;  // pads: never counted (mid>=1)

  // ---- per key-tile: stage K -> QK MFMA (3-pass split) -> St -> capture ----
#pragma unroll
  for (int t = 0; t < 4; ++t) {
    if (t < nt) {
      const int kbt = kbase(t);
      __syncthreads();  // prev tile frag reads + St capture done
      for (int idx = tid; idx < 64 * 32; idx += 512) {
        const int row = idx >> 5, c4 = idx & 31;
        f32x4 v = *(const f32x4*)(kf + (size_t)(b * SS + kbt + row) * HIDC +
                                  h * HD + c4 * 4);
        u16x4 hh, ll;
#pragma unroll
        for (int e = 0; e < 4; ++e) {
          const u16 hi = f2bf(v[e]);
          hh[e] = hi;
          ll[e] = f2bf(v[e] - bf2f(hi));
        }
        const int off = row * 128 + (((c4 >> 1) ^ (row & 7)) << 3) + (c4 & 1) * 4;
        *(u16x4*)(Kh + off) = hh;
        *(u16x4*)(Kl + off) = ll;
      }
      __syncthreads();

      f32x4 acc0 = (f32x4){0.f, 0.f, 0.f, 0.f};
      f32x4 acc1 = (f32x4){0.f, 0.f, 0.f, 0.f};
#pragma unroll
      for (int kt = 0; kt < 4; ++kt) {
        const int kg = kt * 4 + lhi;
#pragma unroll
        for (int ni = 0; ni < 2; ++ni) {
          const int key = nh * 32 + ni * 16 + l15;
          const int off = key * 128 + ((kg ^ (key & 7)) << 3);
          bf16x8 bh = *(const bf16x8*)(Kh + off);
          bf16x8 bl = *(const bf16x8*)(Kl + off);
          f32x4 a = ni ? acc1 : acc0;
          a = __builtin_amdgcn_mfma_f32_16x16x32_bf16(
              __builtin_bit_cast(bf16x8, ah[kt]), bh, a, 0, 0, 0);
          a = __builtin_amdgcn_mfma_f32_16x16x32_bf16(
              __builtin_bit_cast(bf16x8, ah[kt]), bl, a, 0, 0, 0);
          a = __builtin_amdgcn_mfma_f32_16x16x32_bf16(
              __builtin_bit_cast(bf16x8, al[kt]), bh, a, 0, 0, 0);
          if (ni) acc1 = a; else acc0 = a;
        }
      }
#pragma unroll
      for (int ni = 0; ni < 2; ++ni)
#pragma unroll
        for (int r = 0; r < 4; ++r)
          St[(mt * 16 + lhi * 4 + r) * 68 + nh * 32 + ni * 16 + l15] =
              (ni ? acc1 : acc0)[r] * scale;
      __syncthreads();

#pragma unroll
      for (int i = 0; i < 8; ++i) {
        const int r = wv * 8 + i, qi = q0 + r;
        const int key = kbt + lane;
        const bool valid =
            key <= qi && (key >= qi - 127 || key < 16) &&
            !(fm[t * 64 + lane] && key >= 16 && key != qi);
        const float sv = valid ? St[r * 68 + lane] : NEGV;
        uu[i][t] = fmap(sv);
      }
    }
  }
  __syncthreads();  // capture complete; St and KP reusable

  stage_vt(0);  // V^T tile 0 in flight during the search

  // ---- interleaved exact top-k (8 rows, 32 iterations) ----
  u32 tl[8], th[8];
#pragma unroll
  for (int i = 0; i < 8; ++i) { tl[i] = 0u; th[i] = 0xFFFFFFFFu; }
  for (int it = 0; it < 32; ++it) {
#pragma unroll
    for (int i = 0; i < 8; ++i) {
      const u32 mid = tl[i] + ((th[i] - tl[i]) >> 1) + 1u;
      const int cnt = __popcll(__ballot(uu[i][0] >= mid)) +
                      __popcll(__ballot(uu[i][1] >= mid)) +
                      __popcll(__ballot(uu[i][2] >= mid)) +
                      __popcll(__ballot(uu[i][3] >= mid));
      const bool ge = cnt >= KTOP;
      tl[i] = ge ? mid : tl[i];
      th[i] = ge ? th[i] : mid - 1u;
    }
  }

  // ---- softmax (interleaved) ----
  float mrow[8];
#pragma unroll
  for (int i = 0; i < 8; ++i) {
    float mm = NEGV;
#pragma unroll
    for (int j = 0; j < 4; ++j) {
      const float s = unfmap(uu[i][j]);
      mm = (uu[i][j] >= tl[i]) ? fmaxf(mm, s) : mm;
    }
    mrow[i] = mm;
  }
#pragma unroll
  for (int off = 32; off > 0; off >>= 1)
#pragma unroll
    for (int i = 0; i < 8; ++i) mrow[i] = fmaxf(mrow[i], __shfl_xor(mrow[i], off));

  float zrow[8];
#pragma unroll
  for (int i = 0; i < 8; ++i) {
    float zz = 0.f;
#pragma unroll
    for (int j = 0; j < 4; ++j) {
      const float s = unfmap(uu[i][j]);
      zz += (uu[i][j] >= tl[i]) ? __expf(s - mrow[i]) : 0.f;
    }
    zrow[i] = zz;
  }
#pragma unroll
  for (int off = 32; off > 0; off >>= 1)
#pragma unroll
    for (int i = 0; i < 8; ++i) zrow[i] += __shfl_xor(zrow[i], off);

  // ---- write P (bf16, swizzled) over the dead K area ----
#pragma unroll
  for (int i = 0; i < 8; ++i) {
    const int r = wv * 8 + i;
    const float rz = 1.f / zrow[i];
#pragma unroll
    for (int j = 0; j < 4; ++j) {
      const float s = unfmap(uu[i][j]);
      const float p =
          (uu[i][j] >= tl[i]) ? __expf(s - mrow[i]) * rz : 0.f;
      const int c = lane + 64 * j;
      const int sl = c >> 3;
      Pb[r * 256 + ((sl ^ (r & 7)) << 3) + (c & 7)] = f2bf(p);
    }
  }

  asm volatile("s_waitcnt vmcnt(0)" ::: "memory");
  __syncthreads();  // P visible + V^T tile 0 staged

  // ---- PV via MFMA: out[64q][128d] += P[.,tile] @ V^T[tile] ----
  f32x4 pacc[4];
#pragma unroll
  for (int t2 = 0; t2 < 4; ++t2) pacc[t2] = (f32x4){0.f, 0.f, 0.f, 0.f};

#pragma unroll
  for (int t = 0; t < 4; ++t) {
    if (t < nt) {
#pragma unroll
      for (int ks = 0; ks < 2; ++ks) {
        const int arow = mt * 16 + l15;
        const int aslot = t * 8 + ks * 4 + lhi;
        const bf16x8 af =
            *(const bf16x8*)(Pb + arow * 256 + ((aslot ^ (arow & 7)) << 3));
#pragma unroll
        for (int t2 = 0; t2 < 4; ++t2) {
          const int drow = nh * 64 + t2 * 16 + l15;
          const int dslot = ks * 4 + lhi;
          const bf16x8 bf_ =
              *(const bf16x8*)(Vts + drow * 64 + ((dslot ^ (drow & 7)) << 3));
          pacc[t2] = __builtin_amdgcn_mfma_f32_16x16x32_bf16(af, bf_, pacc[t2],
                                                             0, 0, 0);
        }
      }
      if (t + 1 < nt) {
        __syncthreads();  // Vts reads done
        stage_vt(t + 1);
        asm volatile("s_waitcnt vmcnt(0)" ::: "memory");
        __syncthreads();  // next tile ready
      }
    }
  }

  // ---- epilogue: acc -> ab (bf16) ----
#pragma unroll
  for (int t2 = 0; t2 < 4; ++t2)
#pragma unroll
    for (int r = 0; r < 4; ++r) {
      const int row = q0 + mt * 16 + lhi * 4 + r;
      const int col = h * HD + nh * 64 + t2 * 16 + l15;
      ab[(size_t)(b * SS + row) * HIDC + col] = f2bf(pacc[t2][r]);
    }
}

// ----------------------------------------------------------------------------
extern "C" void kernel_launch(void* const* d_in, const int* in_sizes, int n_in,
                              void* d_out, int out_size, void* d_ws, size_t ws_size,
                              hipStream_t stream) {
  const float* x = (const float*)d_in[0];
  const float* W_q = (const float*)d_in[1];
  const float* W_dkv = (const float*)d_in[2];
  const float* W_uk = (const float*)d_in[3];
  const float* W_uv = (const float*)d_in[4];
  const float* W_o = (const float*)d_in[5];
  const int* forget = (const int*)d_in[6];
  const int* topk = (const int*)d_in[7];
  float* out = (float*)d_out;

  char* p = (char*)d_ws;
  auto take = [&](size_t n) {
    char* r = p;
    p += (n + 255) & ~(size_t)255;
    return r;
  };

  u16* xb_hi = (u16*)take((size_t)MROWS * HIDC * 2);  // 16MB
  u16* xb_lo = (u16*)take((size_t)MROWS * HIDC * 2);  // 16MB
  u16* Wqh = (u16*)take((size_t)HIDC * HIDC * 2);     // 8MB
  u16* Wql = (u16*)take((size_t)HIDC * HIDC * 2);     // 8MB
  u16* Wdh = (u16*)take((size_t)LATC * HIDC * 2);     // 2MB  (W_dkv^T)
  u16* Wdl = (u16*)take((size_t)LATC * HIDC * 2);
  u16* Wukh = (u16*)take((size_t)HIDC * LATC * 2);    // 2MB  (W_uk^T)
  u16* Wukl = (u16*)take((size_t)HIDC * LATC * 2);
  u16* Wuvt = (u16*)take((size_t)HIDC * LATC * 2);    // 2MB  (W_uv^T)
  u16* Wot = (u16*)take((size_t)HIDC * HIDC * 2);     // 8MB
  float* qf = (float*)take((size_t)MROWS * HIDC * 4); // 32MB
  float* cf = (float*)take((size_t)MROWS * LATC * 4); // 8MB
  u16* cbh = (u16*)take((size_t)MROWS * LATC * 2);    // 4MB
  u16* cbl = (u16*)take((size_t)MROWS * LATC * 2);    // 4MB
  u16* vt = (u16*)take((size_t)BB * HIDC * SS * 2);   // 16MB (V^T per batch)
  float* kf = (float*)xb_hi;  // alias: xb dead after c-GEMM
  u16* ab = Wqh;              // alias: Wq dead after q-GEMM

  const dim3 tb(32, 32);
  split_ew<<<dim3((MROWS * HIDC / 4) / 256), dim3(256), 0, stream>>>(
      x, xb_hi, xb_lo, MROWS * HIDC);
  transpose_split<<<dim3(HIDC / 32, HIDC / 32), tb, 0, stream>>>(W_q, Wqh, Wql, HIDC, HIDC);
  transpose_split<<<dim3(LATC / 32, HIDC / 32), tb, 0, stream>>>(W_dkv, Wdh, Wdl, HIDC, LATC);
  transpose_split<<<dim3(HIDC / 32, LATC / 32), tb, 0, stream>>>(W_uk, Wukh, Wukl, LATC, HIDC);
  transpose_one<<<dim3(HIDC / 32, LATC / 32), tb, 0, stream>>>(W_uv, Wuvt, LATC, HIDC);
  transpose_one<<<dim3(HIDC / 32, HIDC / 32), tb, 0, stream>>>(W_o, Wot, HIDC, HIDC);

  const dim3 gq(MROWS / 128, HIDC / 128);  // 32 x 16
  const dim3 gc(MROWS / 128, LATC / 128);  // 32 x 4
  const dim3 gv(HIDC / 128, SS / 128);     // 16 x 16 (V^T per batch)

  // q = x @ W_q  (split-bf16, 3 passes -> f32-accurate)
  gemm_bt<0><<<gq, 256, 0, stream>>>(xb_hi, Wqh, qf, nullptr, MROWS, HIDC, HIDC);
  gemm_bt<1><<<gq, 256, 0, stream>>>(xb_hi, Wql, qf, nullptr, MROWS, HIDC, HIDC);
  gemm_bt<1><<<gq, 256, 0, stream>>>(xb_lo, Wqh, qf, nullptr, MROWS, HIDC, HIDC);
  // c = x @ W_dkv (split-bf16)
  gemm_bt<0><<<gc, 256, 0, stream>>>(xb_hi, Wdh, cf, nullptr, MROWS, LATC, HIDC);
  gemm_bt<1><<<gc, 256, 0, stream>>>(xb_hi, Wdl, cf, nullptr, MROWS, LATC, HIDC);
  gemm_bt<1><<<gc, 256, 0, stream>>>(xb_lo, Wdh, cf, nullptr, MROWS, LATC, HIDC);
  split_ew<<<dim3((MROWS * LATC / 4) / 256), dim3(256), 0, stream>>>(
      cf, cbh, cbl, MROWS * LATC);
  // k = c @ W_uk (split-bf16)  -- kf aliases xb (dead now)
  gemm_bt<0><<<gq, 256, 0, stream>>>(cbh, Wukh, kf, nullptr, MROWS, HIDC, LATC);
  gemm_bt<1><<<gq, 256, 0, stream>>>(cbh, Wukl, kf, nullptr, MROWS, HIDC, LATC);
  gemm_bt<1><<<gq, 256, 0, stream>>>(cbl, Wukh, kf, nullptr, MROWS, HIDC, LATC);
  // v^T = W_uv^T @ c_b^T per batch: same GEMM kernel, swapped operands
  gemm_bt<2><<<gv, 256, 0, stream>>>(Wuvt, cbh, nullptr, vt, HIDC, SS, LATC);
  gemm_bt<2><<<gv, 256, 0, stream>>>(Wuvt, cbh + (size_t)SS * LATC, nullptr,
                                     vt + (size_t)HIDC * SS, HIDC, SS, LATC);
  // attention v3 -> ab (bf16), aliases Wq (dead)
  attn_v3<<<dim3(SS / 64, NH, BB), dim3(512), 0, stream>>>(
      qf, kf, vt, forget, topk, ab);
  // out = attn_out @ W_o
  gemm_bt<0><<<gq, 256, 0, stream>>>(ab, Wot, out, nullptr, MROWS, HIDC, HIDC);
}

// Round 4
// 358.061 us; speedup vs baseline: 3.0415x; 1.4765x over previous
//
#include <hip/hip_runtime.h>
#include <hip/hip_bf16.h>

typedef unsigned short u16;
typedef unsigned int u32;
typedef unsigned long long u64;
typedef __bf16 bf16x8 __attribute__((ext_vector_type(8)));
typedef float f32x4 __attribute__((ext_vector_type(4)));
typedef u16 u16x4 __attribute__((ext_vector_type(4)));
typedef u16 u16x8 __attribute__((ext_vector_type(8)));

static constexpr int BB = 2, SS = 2048, HIDC = 2048, LATC = 512, NH = 16, HD = 128;
static constexpr int MROWS = BB * SS;  // 4096
static constexpr float NEGV = -1e9f;

__device__ __forceinline__ u16 f2bf(float f) {
  __hip_bfloat16 h = __float2bfloat16(f);
  return __builtin_bit_cast(u16, h);
}
__device__ __forceinline__ float bf2f(u16 u) {
  return __uint_as_float(((u32)u) << 16);
}
__device__ __forceinline__ void load_lds16(const void* g, void* l) {
  __builtin_amdgcn_global_load_lds(
      (const __attribute__((address_space(1))) void*)g,
      (__attribute__((address_space(3))) void*)l, 16, 0, 0);
}

// ---------------- plain GEMM: C[M][N] = A[M][K] @ Bt[N][K]^T ----------------
// MODE 0: C = f32 store; MODE 2: Cb = bf16 store
template <int MODE>
__global__ __launch_bounds__(256, 2) void gemm_bt(
    const u16* __restrict__ A, const u16* __restrict__ Bt,
    float* __restrict__ C, u16* __restrict__ Cb, int M, int N, int K) {
  __shared__ u16 As[128 * 64];
  __shared__ u16 Bs[128 * 64];
  const int tid = threadIdx.x;
  const int lane = tid & 63;
  const int wv = tid >> 6;
  const int wr = wv >> 1, wc = wv & 1;
  const int m0 = blockIdx.x * 128, n0 = blockIdx.y * 128;

  f32x4 acc[4][4];
#pragma unroll
  for (int i = 0; i < 4; ++i)
#pragma unroll
    for (int j = 0; j < 4; ++j) acc[i][j] = (f32x4){0.f, 0.f, 0.f, 0.f};

  int srow[4], sgc[4];
#pragma unroll
  for (int j = 0; j < 4; ++j) {
    int e = j * 2048 + tid * 8;
    int row = e >> 6;
    int slot = (e >> 3) & 7;
    srow[j] = row;
    sgc[j] = (slot ^ (row & 7)) * 8;
  }

  for (int k0 = 0; k0 < K; k0 += 64) {
    __syncthreads();
#pragma unroll
    for (int j = 0; j < 4; ++j) {
      const u16* ga = A + (size_t)(m0 + srow[j]) * K + k0 + sgc[j];
      const u16* gb = Bt + (size_t)(n0 + srow[j]) * K + k0 + sgc[j];
      load_lds16(ga, &As[j * 2048 + wv * 512]);
      load_lds16(gb, &Bs[j * 2048 + wv * 512]);
    }
    asm volatile("s_waitcnt vmcnt(0)" ::: "memory");
    __syncthreads();

#pragma unroll
    for (int kk = 0; kk < 2; ++kk) {
      bf16x8 afr[4], bfr[4];
      const int kg = kk * 4 + (lane >> 4);
#pragma unroll
      for (int i = 0; i < 4; ++i) {
        int ar = wr * 64 + i * 16 + (lane & 15);
        afr[i] = *(const bf16x8*)&As[ar * 64 + ((kg ^ (ar & 7)) << 3)];
        int br = wc * 64 + i * 16 + (lane & 15);
        bfr[i] = *(const bf16x8*)&Bs[br * 64 + ((kg ^ (br & 7)) << 3)];
      }
#pragma unroll
      for (int mi = 0; mi < 4; ++mi)
#pragma unroll
        for (int ni = 0; ni < 4; ++ni)
          acc[mi][ni] = __builtin_amdgcn_mfma_f32_16x16x32_bf16(
              afr[mi], bfr[ni], acc[mi][ni], 0, 0, 0);
    }
  }

#pragma unroll
  for (int mi = 0; mi < 4; ++mi) {
#pragma unroll
    for (int ni = 0; ni < 4; ++ni) {
      const int row = m0 + wr * 64 + mi * 16 + (lane >> 4) * 4;
      const int col = n0 + wc * 64 + ni * 16 + (lane & 15);
#pragma unroll
      for (int r = 0; r < 4; ++r) {
        size_t off = (size_t)(row + r) * N + col;
        if constexpr (MODE == 0) C[off] = acc[mi][ni][r];
        if constexpr (MODE == 2) Cb[off] = f2bf(acc[mi][ni][r]);
      }
    }
  }
}

// -------- fused split GEMM: C = Ah@Bh^T + Ah@Bl^T + Al@Bh^T (f32-accurate) --
// TN: N-tile width (128 or 64). M-tile fixed 128, BK=64, 4 waves (2x2).
template <int TN, int MODE>
__global__ __launch_bounds__(256, 2) void gemm_split_bt(
    const u16* __restrict__ Ah, const u16* __restrict__ Al,
    const u16* __restrict__ Bth, const u16* __restrict__ Btl,
    float* __restrict__ C, u16* __restrict__ Cb, int M, int N, int K) {
  constexpr int NI = TN / 32;  // 16-col frags per wave
  __shared__ u16 Ash[128 * 64];
  __shared__ u16 Asl[128 * 64];
  __shared__ u16 Bsh[TN * 64];
  __shared__ u16 Bsl[TN * 64];
  const int tid = threadIdx.x;
  const int lane = tid & 63;
  const int wv = tid >> 6;
  const int wr = wv >> 1, wc = wv & 1;
  const int l15 = lane & 15, lhi = lane >> 4;
  const int m0 = blockIdx.x * 128, n0 = blockIdx.y * TN;

  f32x4 acc[4][NI];
#pragma unroll
  for (int i = 0; i < 4; ++i)
#pragma unroll
    for (int j = 0; j < NI; ++j) acc[i][j] = (f32x4){0.f, 0.f, 0.f, 0.f};

  int srow[4], sgc[4];
#pragma unroll
  for (int j = 0; j < 4; ++j) {
    int e = j * 2048 + tid * 8;
    int row = e >> 6;
    int slot = (e >> 3) & 7;
    srow[j] = row;
    sgc[j] = (slot ^ (row & 7)) * 8;
  }

  for (int k0 = 0; k0 < K; k0 += 64) {
    __syncthreads();
#pragma unroll
    for (int j = 0; j < 4; ++j) {
      const size_t ao = (size_t)(m0 + srow[j]) * K + k0 + sgc[j];
      load_lds16(Ah + ao, &Ash[j * 2048 + wv * 512]);
      load_lds16(Al + ao, &Asl[j * 2048 + wv * 512]);
    }
#pragma unroll
    for (int j = 0; j < NI; ++j) {
      const size_t bo = (size_t)(n0 + srow[j]) * K + k0 + sgc[j];
      load_lds16(Bth + bo, &Bsh[j * 2048 + wv * 512]);
      load_lds16(Btl + bo, &Bsl[j * 2048 + wv * 512]);
    }
    asm volatile("s_waitcnt vmcnt(0)" ::: "memory");
    __syncthreads();

#pragma unroll
    for (int kk = 0; kk < 2; ++kk) {
      const int kg = kk * 4 + lhi;
      bf16x8 afh[4], afl[4], bfh[NI], bfl[NI];
#pragma unroll
      for (int i = 0; i < 4; ++i) {
        const int ar = wr * 64 + i * 16 + l15;
        const int off = ar * 64 + ((kg ^ (ar & 7)) << 3);
        afh[i] = *(const bf16x8*)&Ash[off];
        afl[i] = *(const bf16x8*)&Asl[off];
      }
#pragma unroll
      for (int i = 0; i < NI; ++i) {
        const int br = wc * (TN / 2) + i * 16 + l15;
        const int off = br * 64 + ((kg ^ (br & 7)) << 3);
        bfh[i] = *(const bf16x8*)&Bsh[off];
        bfl[i] = *(const bf16x8*)&Bsl[off];
      }
#pragma unroll
      for (int mi = 0; mi < 4; ++mi)
#pragma unroll
        for (int ni = 0; ni < NI; ++ni) {
          acc[mi][ni] = __builtin_amdgcn_mfma_f32_16x16x32_bf16(
              afh[mi], bfh[ni], acc[mi][ni], 0, 0, 0);
          acc[mi][ni] = __builtin_amdgcn_mfma_f32_16x16x32_bf16(
              afh[mi], bfl[ni], acc[mi][ni], 0, 0, 0);
          acc[mi][ni] = __builtin_amdgcn_mfma_f32_16x16x32_bf16(
              afl[mi], bfh[ni], acc[mi][ni], 0, 0, 0);
        }
    }
  }

#pragma unroll
  for (int mi = 0; mi < 4; ++mi) {
#pragma unroll
    for (int ni = 0; ni < NI; ++ni) {
      const int row = m0 + wr * 64 + mi * 16 + lhi * 4;
      const int col = n0 + wc * (TN / 2) + ni * 16 + l15;
#pragma unroll
      for (int r = 0; r < 4; ++r) {
        size_t off = (size_t)(row + r) * N + col;
        if constexpr (MODE == 0) C[off] = acc[mi][ni][r];
        if constexpr (MODE == 2) Cb[off] = f2bf(acc[mi][ni][r]);
      }
    }
  }
}

// ------------- transpose + convert: W[K][N] f32 -> Wt[N][K] bf16 (hi/lo) ----
__global__ __launch_bounds__(1024) void transpose_split(
    const float* __restrict__ W, u16* __restrict__ Th, u16* __restrict__ Tl,
    int K, int N) {
  __shared__ float t[32][33];
  const int tx = threadIdx.x, ty = threadIdx.y;
  t[ty][tx] = W[(size_t)(blockIdx.y * 32 + ty) * N + blockIdx.x * 32 + tx];
  __syncthreads();
  const float v = t[tx][ty];
  const u16 hi = f2bf(v);
  const u16 lo = f2bf(v - bf2f(hi));
  const size_t o = (size_t)(blockIdx.x * 32 + ty) * K + blockIdx.y * 32 + tx;
  Th[o] = hi;
  Tl[o] = lo;
}

__global__ __launch_bounds__(1024) void transpose_one(
    const float* __restrict__ W, u16* __restrict__ T, int K, int N) {
  __shared__ float t[32][33];
  const int tx = threadIdx.x, ty = threadIdx.y;
  t[ty][tx] = W[(size_t)(blockIdx.y * 32 + ty) * N + blockIdx.x * 32 + tx];
  __syncthreads();
  const size_t o = (size_t)(blockIdx.x * 32 + ty) * K + blockIdx.y * 32 + tx;
  T[o] = f2bf(t[tx][ty]);
}

// ------------- elementwise split: f32 -> bf16 hi + bf16 lo ------------------
__global__ void split_ew(const float* __restrict__ in, u16* __restrict__ hi,
                         u16* __restrict__ lo, int n) {
  const size_t i = ((size_t)blockIdx.x * blockDim.x + threadIdx.x) * 4;
  if (i >= (size_t)n) return;
  f32x4 v = *(const f32x4*)(in + i);
  u16x4 h, l;
#pragma unroll
  for (int e = 0; e < 4; ++e) {
    float f = v[e];
    u16 hh = f2bf(f);
    h[e] = hh;
    l[e] = f2bf(f - bf2f(hh));
  }
  *(u16x4*)(hi + i) = h;
  *(u16x4*)(lo + i) = l;
}

// ------------- attention v3 (unchanged from R3) ------------------------------
__device__ __forceinline__ u32 fmap(float f) {
  u32 b = __float_as_uint(f);
  return (b & 0x80000000u) ? ~b : (b | 0x80000000u);
}
__device__ __forceinline__ float unfmap(u32 u) {
  return (u & 0x80000000u) ? __uint_as_float(u ^ 0x80000000u)
                           : __uint_as_float(~u);
}

__global__ __launch_bounds__(512, 4) void attn_v3(
    const float* __restrict__ qf, const float* __restrict__ kf,
    const u16* __restrict__ vt, const int* __restrict__ forget,
    const int* __restrict__ topk, u16* __restrict__ ab) {
  __shared__ u16 KP[2 * 64 * 128];  // 32KB: K hi/lo tiles; later P[64][256]
  __shared__ float St[64 * 68];     // 17KB: per-tile scores; later V^T tile
  __shared__ int fm[256];           // 1KB

  u16* const Kh = KP;
  u16* const Kl = KP + 64 * 128;
  u16* const Pb = KP;          // P bf16 [64][256], slot-XOR swizzled
  u16* const Vts = (u16*)St;   // V^T tile [128 d][64 k], slot-XOR swizzled

  const float scale = 0.08838834764831845f;  // 1/sqrt(128)
  const int tid = threadIdx.x, lane = tid & 63, wv = tid >> 6;
  const int q0 = blockIdx.x * 64;
  const int h = blockIdx.y, b = blockIdx.z;
  const int mt = wv >> 1, nh = wv & 1;
  const int l15 = lane & 15, lhi = lane >> 4;

  const int nt = (q0 >= 256) ? 4 : (q0 / 64 + 1);
  const int KTOP = topk[0];

  auto kbase = [&](int t) {
    return (q0 >= 256) ? (t == 0 ? 0 : q0 + t * 64 - 192) : t * 64;
  };
  auto stage_vt = [&](int T) {
    const int kbt = kbase(T);
#pragma unroll
    for (int p = 0; p < 2; ++p) {
      const int c = p * 512 + tid;
      const int d = c >> 3, sl = c & 7;
      const u16* src = vt + ((size_t)(b * HIDC + h * HD + d)) * SS + kbt +
                       ((sl ^ (d & 7)) << 3);
      load_lds16(src, Vts + (p * 512 + wv * 64) * 8);
    }
  };

  if (tid < 256) {
    const int t = tid >> 6;
    fm[tid] = (t < nt) ? forget[b * SS + kbase(t) + (tid & 63)] : 0;
  }

  u16x8 ah[4], al[4];
  {
    const size_t qrow = (size_t)(b * SS + q0 + mt * 16 + l15) * HIDC + h * HD;
#pragma unroll
    for (int kt = 0; kt < 4; ++kt)
#pragma unroll
      for (int hf = 0; hf < 2; ++hf) {
        f32x4 v = *(const f32x4*)(qf + qrow + kt * 32 + lhi * 8 + hf * 4);
#pragma unroll
        for (int e = 0; e < 4; ++e) {
          const u16 hi = f2bf(v[e]);
          ah[kt][hf * 4 + e] = hi;
          al[kt][hf * 4 + e] = f2bf(v[e] - bf2f(hi));
        }
      }
  }

  u32 uu[8][4];
#pragma unroll
  for (int i = 0; i < 8; ++i)
#pragma unroll
    for (int j = 0; j < 4; ++j) uu[i][j] = 0u;

#pragma unroll
  for (int t = 0; t < 4; ++t) {
    if (t < nt) {
      const int kbt = kbase(t);
      __syncthreads();
      for (int idx = tid; idx < 64 * 32; idx += 512) {
        const int row = idx >> 5, c4 = idx & 31;
        f32x4 v = *(const f32x4*)(kf + (size_t)(b * SS + kbt + row) * HIDC +
                                  h * HD + c4 * 4);
        u16x4 hh, ll;
#pragma unroll
        for (int e = 0; e < 4; ++e) {
          const u16 hi = f2bf(v[e]);
          hh[e] = hi;
          ll[e] = f2bf(v[e] - bf2f(hi));
        }
        const int off = row * 128 + (((c4 >> 1) ^ (row & 7)) << 3) + (c4 & 1) * 4;
        *(u16x4*)(Kh + off) = hh;
        *(u16x4*)(Kl + off) = ll;
      }
      __syncthreads();

      f32x4 acc0 = (f32x4){0.f, 0.f, 0.f, 0.f};
      f32x4 acc1 = (f32x4){0.f, 0.f, 0.f, 0.f};
#pragma unroll
      for (int kt = 0; kt < 4; ++kt) {
        const int kg = kt * 4 + lhi;
#pragma unroll
        for (int ni = 0; ni < 2; ++ni) {
          const int key = nh * 32 + ni * 16 + l15;
          const int off = key * 128 + ((kg ^ (key & 7)) << 3);
          bf16x8 bh = *(const bf16x8*)(Kh + off);
          bf16x8 bl = *(const bf16x8*)(Kl + off);
          f32x4 a = ni ? acc1 : acc0;
          a = __builtin_amdgcn_mfma_f32_16x16x32_bf16(
              __builtin_bit_cast(bf16x8, ah[kt]), bh, a, 0, 0, 0);
          a = __builtin_amdgcn_mfma_f32_16x16x32_bf16(
              __builtin_bit_cast(bf16x8, ah[kt]), bl, a, 0, 0, 0);
          a = __builtin_amdgcn_mfma_f32_16x16x32_bf16(
              __builtin_bit_cast(bf16x8, al[kt]), bh, a, 0, 0, 0);
          if (ni) acc1 = a; else acc0 = a;
        }
      }
#pragma unroll
      for (int ni = 0; ni < 2; ++ni)
#pragma unroll
        for (int r = 0; r < 4; ++r)
          St[(mt * 16 + lhi * 4 + r) * 68 + nh * 32 + ni * 16 + l15] =
              (ni ? acc1 : acc0)[r] * scale;
      __syncthreads();

#pragma unroll
      for (int i = 0; i < 8; ++i) {
        const int r = wv * 8 + i, qi = q0 + r;
        const int key = kbt + lane;
        const bool valid =
            key <= qi && (key >= qi - 127 || key < 16) &&
            !(fm[t * 64 + lane] && key >= 16 && key != qi);
        const float sv = valid ? St[r * 68 + lane] : NEGV;
        uu[i][t] = fmap(sv);
      }
    }
  }
  __syncthreads();

  stage_vt(0);

  u32 tl[8], th[8];
#pragma unroll
  for (int i = 0; i < 8; ++i) { tl[i] = 0u; th[i] = 0xFFFFFFFFu; }
  for (int it = 0; it < 32; ++it) {
#pragma unroll
    for (int i = 0; i < 8; ++i) {
      const u32 mid = tl[i] + ((th[i] - tl[i]) >> 1) + 1u;
      const int cnt = __popcll(__ballot(uu[i][0] >= mid)) +
                      __popcll(__ballot(uu[i][1] >= mid)) +
                      __popcll(__ballot(uu[i][2] >= mid)) +
                      __popcll(__ballot(uu[i][3] >= mid));
      const bool ge = cnt >= KTOP;
      tl[i] = ge ? mid : tl[i];
      th[i] = ge ? th[i] : mid - 1u;
    }
  }

  float mrow[8];
#pragma unroll
  for (int i = 0; i < 8; ++i) {
    float mm = NEGV;
#pragma unroll
    for (int j = 0; j < 4; ++j) {
      const float s = unfmap(uu[i][j]);
      mm = (uu[i][j] >= tl[i]) ? fmaxf(mm, s) : mm;
    }
    mrow[i] = mm;
  }
#pragma unroll
  for (int off = 32; off > 0; off >>= 1)
#pragma unroll
    for (int i = 0; i < 8; ++i) mrow[i] = fmaxf(mrow[i], __shfl_xor(mrow[i], off));

  float zrow[8];
#pragma unroll
  for (int i = 0; i < 8; ++i) {
    float zz = 0.f;
#pragma unroll
    for (int j = 0; j < 4; ++j) {
      const float s = unfmap(uu[i][j]);
      zz += (uu[i][j] >= tl[i]) ? __expf(s - mrow[i]) : 0.f;
    }
    zrow[i] = zz;
  }
#pragma unroll
  for (int off = 32; off > 0; off >>= 1)
#pragma unroll
    for (int i = 0; i < 8; ++i) zrow[i] += __shfl_xor(zrow[i], off);

#pragma unroll
  for (int i = 0; i < 8; ++i) {
    const int r = wv * 8 + i;
    const float rz = 1.f / zrow[i];
#pragma unroll
    for (int j = 0; j < 4; ++j) {
      const float s = unfmap(uu[i][j]);
      const float p =
          (uu[i][j] >= tl[i]) ? __expf(s - mrow[i]) * rz : 0.f;
      const int c = lane + 64 * j;
      const int sl = c >> 3;
      Pb[r * 256 + ((sl ^ (r & 7)) << 3) + (c & 7)] = f2bf(p);
    }
  }

  asm volatile("s_waitcnt vmcnt(0)" ::: "memory");
  __syncthreads();

  f32x4 pacc[4];
#pragma unroll
  for (int t2 = 0; t2 < 4; ++t2) pacc[t2] = (f32x4){0.f, 0.f, 0.f, 0.f};

#pragma unroll
  for (int t = 0; t < 4; ++t) {
    if (t < nt) {
#pragma unroll
      for (int ks = 0; ks < 2; ++ks) {
        const int arow = mt * 16 + l15;
        const int aslot = t * 8 + ks * 4 + lhi;
        const bf16x8 af =
            *(const bf16x8*)(Pb + arow * 256 + ((aslot ^ (arow & 7)) << 3));
#pragma unroll
        for (int t2 = 0; t2 < 4; ++t2) {
          const int drow = nh * 64 + t2 * 16 + l15;
          const int dslot = ks * 4 + lhi;
          const bf16x8 bf_ =
              *(const bf16x8*)(Vts + drow * 64 + ((dslot ^ (drow & 7)) << 3));
          pacc[t2] = __builtin_amdgcn_mfma_f32_16x16x32_bf16(af, bf_, pacc[t2],
                                                             0, 0, 0);
        }
      }
      if (t + 1 < nt) {
        __syncthreads();
        stage_vt(t + 1);
        asm volatile("s_waitcnt vmcnt(0)" ::: "memory");
        __syncthreads();
      }
    }
  }

#pragma unroll
  for (int t2 = 0; t2 < 4; ++t2)
#pragma unroll
    for (int r = 0; r < 4; ++r) {
      const int row = q0 + mt * 16 + lhi * 4 + r;
      const int col = h * HD + nh * 64 + t2 * 16 + l15;
      ab[(size_t)(b * SS + row) * HIDC + col] = f2bf(pacc[t2][r]);
    }
}

// ----------------------------------------------------------------------------
extern "C" void kernel_launch(void* const* d_in, const int* in_sizes, int n_in,
                              void* d_out, int out_size, void* d_ws, size_t ws_size,
                              hipStream_t stream) {
  const float* x = (const float*)d_in[0];
  const float* W_q = (const float*)d_in[1];
  const float* W_dkv = (const float*)d_in[2];
  const float* W_uk = (const float*)d_in[3];
  const float* W_uv = (const float*)d_in[4];
  const float* W_o = (const float*)d_in[5];
  const int* forget = (const int*)d_in[6];
  const int* topk = (const int*)d_in[7];
  float* out = (float*)d_out;

  char* p = (char*)d_ws;
  auto take = [&](size_t n) {
    char* r = p;
    p += (n + 255) & ~(size_t)255;
    return r;
  };

  u16* xb_hi = (u16*)take((size_t)MROWS * HIDC * 2);  // 16MB
  u16* xb_lo = (u16*)take((size_t)MROWS * HIDC * 2);  // 16MB
  u16* Wqh = (u16*)take((size_t)HIDC * HIDC * 2);     // 8MB
  u16* Wql = (u16*)take((size_t)HIDC * HIDC * 2);     // 8MB
  u16* Wdh = (u16*)take((size_t)LATC * HIDC * 2);     // 2MB  (W_dkv^T)
  u16* Wdl = (u16*)take((size_t)LATC * HIDC * 2);
  u16* Wukh = (u16*)take((size_t)HIDC * LATC * 2);    // 2MB  (W_uk^T)
  u16* Wukl = (u16*)take((size_t)HIDC * LATC * 2);
  u16* Wuvt = (u16*)take((size_t)HIDC * LATC * 2);    // 2MB  (W_uv^T)
  u16* Wot = (u16*)take((size_t)HIDC * HIDC * 2);     // 8MB
  float* qf = (float*)take((size_t)MROWS * HIDC * 4); // 32MB
  float* cf = (float*)take((size_t)MROWS * LATC * 4); // 8MB
  u16* cbh = (u16*)take((size_t)MROWS * LATC * 2);    // 4MB
  u16* cbl = (u16*)take((size_t)MROWS * LATC * 2);    // 4MB
  u16* vt = (u16*)take((size_t)BB * HIDC * SS * 2);   // 16MB (V^T per batch)
  float* kf = (float*)xb_hi;  // alias: xb dead after fused c-GEMM
  u16* ab = Wqh;              // alias: Wq dead after fused q-GEMM

  const dim3 tb(32, 32);
  split_ew<<<dim3((MROWS * HIDC / 4) / 256), dim3(256), 0, stream>>>(
      x, xb_hi, xb_lo, MROWS * HIDC);
  transpose_split<<<dim3(HIDC / 32, HIDC / 32), tb, 0, stream>>>(W_q, Wqh, Wql, HIDC, HIDC);
  transpose_split<<<dim3(LATC / 32, HIDC / 32), tb, 0, stream>>>(W_dkv, Wdh, Wdl, HIDC, LATC);
  transpose_split<<<dim3(HIDC / 32, LATC / 32), tb, 0, stream>>>(W_uk, Wukh, Wukl, LATC, HIDC);
  transpose_one<<<dim3(HIDC / 32, LATC / 32), tb, 0, stream>>>(W_uv, Wuvt, LATC, HIDC);
  transpose_one<<<dim3(HIDC / 32, HIDC / 32), tb, 0, stream>>>(W_o, Wot, HIDC, HIDC);

  // q = x @ W_q (fused split: one launch)
  gemm_split_bt<128, 0><<<dim3(MROWS / 128, HIDC / 128), 256, 0, stream>>>(
      xb_hi, xb_lo, Wqh, Wql, qf, nullptr, MROWS, HIDC, HIDC);
  // c = x @ W_dkv (fused split, 64-wide N-tile -> 256 blocks)
  gemm_split_bt<64, 0><<<dim3(MROWS / 128, LATC / 64), 256, 0, stream>>>(
      xb_hi, xb_lo, Wdh, Wdl, cf, nullptr, MROWS, LATC, HIDC);
  split_ew<<<dim3((MROWS * LATC / 4) / 256), dim3(256), 0, stream>>>(
      cf, cbh, cbl, MROWS * LATC);
  // k = c @ W_uk (fused split) -- kf aliases xb (dead now)
  gemm_split_bt<128, 0><<<dim3(MROWS / 128, HIDC / 128), 256, 0, stream>>>(
      cbh, cbl, Wukh, Wukl, kf, nullptr, MROWS, HIDC, LATC);
  // v^T = W_uv^T @ c_b^T per batch (plain bf16)
  const dim3 gv(HIDC / 128, SS / 128);
  gemm_bt<2><<<gv, 256, 0, stream>>>(Wuvt, cbh, nullptr, vt, HIDC, SS, LATC);
  gemm_bt<2><<<gv, 256, 0, stream>>>(Wuvt, cbh + (size_t)SS * LATC, nullptr,
                                     vt + (size_t)HIDC * SS, HIDC, SS, LATC);
  // attention v3 -> ab (bf16), aliases Wq (dead)
  attn_v3<<<dim3(SS / 64, NH, BB), dim3(512), 0, stream>>>(
      qf, kf, vt, forget, topk, ab);
  // out = attn_out @ W_o
  gemm_bt<0><<<dim3(MROWS / 128, HIDC / 128), 256, 0, stream>>>(
      ab, Wot, out, nullptr, MROWS, HIDC, HIDC);
}